// Round 1
// baseline (188.312 us; speedup 1.0000x reference)
//
#include <hip/hip_runtime.h>
#include <hip/hip_bf16.h>

#define NPTS   16384
#define NPAIRS 65536

// ws layout:
//   [0..32)    : double acc[4]  {partSum, kldRaw, S1, S2}
//   [256.. )   : float4 xt[NPTS]  {x0, x1, x2+1, 0}
// total ~262.4 KB

__device__ inline float waveReduce(float v) {
#pragma unroll
    for (int o = 32; o > 0; o >>= 1) v += __shfl_down(v, o, 64);
    return v;
}

// ---------------- kernel A: reparam table + KLD reduction ----------------
__global__ __launch_bounds__(256) void k_points(
        const float2* __restrict__ mu, const float2* __restrict__ lv,
        const float2* __restrict__ ef, float4* __restrict__ xt,
        double* __restrict__ acc) {
    int i = blockIdx.x * 256 + threadIdx.x;
    float2 m = mu[i], l = lv[i], e = ef[i];
    float x0 = fmaf(e.x, expf(0.5f * l.x), m.x);
    float x1 = fmaf(e.y, expf(0.5f * l.y), m.y);
    float w  = fmaf(x0, x0, x1 * x1) + 1.0f;   // x2 + 1 (fold the "+1" of 1+dkl2)
    xt[i] = make_float4(x0, x1, w, 0.0f);
    // raw kld sum: (1 + lv - mu^2 - exp(lv)) over both dims; -0.5 applied at finalize
    float k = (1.0f + l.x - m.x * m.x - expf(l.x))
            + (1.0f + l.y - m.y * m.y - expf(l.y));
    k = waveReduce(k);
    if ((threadIdx.x & 63) == 0) atomicAdd(&acc[1], (double)k);
}

// ---------------- kernel B: N^2 normalizer (dominant) ----------------
__global__ __launch_bounds__(256) void k_part(
        const float4* __restrict__ xt, double* __restrict__ acc) {
    __shared__ float4 sc[256];
    int row = blockIdx.x * 256 + threadIdx.x;
    float4 r = xt[row];
    float wi = r.z - 1.0f;              // x2_i
    float m0 = -2.0f * r.x, m1 = -2.0f * r.y;
    float a0 = 0.f, a1 = 0.f, a2 = 0.f, a3 = 0.f;
    int cbase = blockIdx.y * 1024;      // 16 column chunks of 1024
    for (int t = 0; t < 1024; t += 256) {
        float4 c = xt[cbase + t + threadIdx.x];
        __syncthreads();
        sc[threadIdx.x] = c;
        __syncthreads();
#pragma unroll 4
        for (int u = 0; u < 256; u += 4) {
            float4 c0 = sc[u],     c1 = sc[u + 1];
            float4 c2 = sc[u + 2], c3 = sc[u + 3];
            float e0 = wi + c0.z; e0 = fmaf(m0, c0.x, e0); e0 = fmaf(m1, c0.y, e0); e0 = fmaxf(e0, 1.0f);
            float e1 = wi + c1.z; e1 = fmaf(m0, c1.x, e1); e1 = fmaf(m1, c1.y, e1); e1 = fmaxf(e1, 1.0f);
            float e2 = wi + c2.z; e2 = fmaf(m0, c2.x, e2); e2 = fmaf(m1, c2.y, e2); e2 = fmaxf(e2, 1.0f);
            float e3 = wi + c3.z; e3 = fmaf(m0, c3.x, e3); e3 = fmaf(m1, c3.y, e3); e3 = fmaxf(e3, 1.0f);
            a0 += __builtin_amdgcn_rcpf(e0);
            a1 += __builtin_amdgcn_rcpf(e1);
            a2 += __builtin_amdgcn_rcpf(e2);
            a3 += __builtin_amdgcn_rcpf(e3);
        }
    }
    float a = (a0 + a1) + (a2 + a3);
    a = waveReduce(a);
    if ((threadIdx.x & 63) == 0) atomicAdd(&acc[0], (double)a);
}

// ---------------- kernel C: per-pair loss terms ----------------
__global__ __launch_bounds__(256) void k_pairs(
        const float* __restrict__ pij, const int* __restrict__ ii,
        const int* __restrict__ jj,
        const float2* __restrict__ mu, const float2* __restrict__ lv,
        const float2* __restrict__ ei, const float2* __restrict__ ej,
        double* __restrict__ acc) {
    int p = blockIdx.x * 256 + threadIdx.x;
    float pv = pij[p];
    int a = ii[p], b = jj[p];
    float2 ma = mu[a], la = lv[a], ea = ei[p];
    float2 mb = mu[b], lb = lv[b], eb = ej[p];
    float xa0 = fmaf(ea.x, expf(0.5f * la.x), ma.x);
    float xa1 = fmaf(ea.y, expf(0.5f * la.y), ma.y);
    float xb0 = fmaf(eb.x, expf(0.5f * lb.x), mb.x);
    float xb1 = fmaf(eb.y, expf(0.5f * lb.y), mb.y);
    float d0 = xa0 - xb0, d1 = xa1 - xb1;
    float dsq = fmaf(d0, d0, d1 * d1);
    // pij*(log pij - log num), with -log num = log1p(dsq)
    float t = pv * (logf(pv) + log1pf(dsq));
    float s1 = waveReduce(t);
    float s2 = waveReduce(pv);
    if ((threadIdx.x & 63) == 0) {
        atomicAdd(&acc[2], (double)s1);
        atomicAdd(&acc[3], (double)s2);
    }
}

// ---------------- kernel D: finalize ----------------
__global__ void k_final(const double* __restrict__ acc, float* __restrict__ out) {
    double part = acc[0] - (double)NPTS;
    double res = acc[2] + acc[3] * log(part) - 0.5e-7 * acc[1];
    out[0] = (float)res;
}

extern "C" void kernel_launch(void* const* d_in, const int* in_sizes, int n_in,
                              void* d_out, int out_size, void* d_ws, size_t ws_size,
                              hipStream_t stream) {
    const float*  pij = (const float*)d_in[0];
    const int*    ii  = (const int*)d_in[1];
    const int*    jj  = (const int*)d_in[2];
    const float2* mu  = (const float2*)d_in[3];
    const float2* lv  = (const float2*)d_in[4];
    const float2* ef  = (const float2*)d_in[5];
    const float2* ei  = (const float2*)d_in[6];
    const float2* ej  = (const float2*)d_in[7];
    float* out  = (float*)d_out;
    double* acc = (double*)d_ws;
    float4* xt  = (float4*)((char*)d_ws + 256);

    hipMemsetAsync(d_ws, 0, 256, stream);
    k_points<<<NPTS / 256, 256, 0, stream>>>(mu, lv, ef, xt, acc);
    k_pairs<<<NPAIRS / 256, 256, 0, stream>>>(pij, ii, jj, mu, lv, ei, ej, acc);
    dim3 gb(NPTS / 256, 16);
    k_part<<<gb, 256, 0, stream>>>(xt, acc);
    k_final<<<1, 1, 0, stream>>>(acc, out);
}